// Round 6
// baseline (435.750 us; speedup 1.0000x reference)
//
#include <hip/hip_runtime.h>
#include <math.h>

#define NB 16
#define NC 64
#define HW 160
#define PLANE (HW * HW)               // 25600
#define SG 161                        // site grid (H+1)
#define SGSQ (SG * SG)                // 25921
#define NSITES (NB * SGSQ)            // 414736
#define OUT_LD_OFF (NB * NC * PLANE)  // logdet output offset
#define TILE 256                      // sites per conv block
#define NCONV ((NSITES + TILE - 1) / TILE)  // 1621

// Conv blocks use vtile[32 krows][256 sites] = 8192 floats (32 KB).
// Det block only needs partial[4] (overlaid at smem[0..3]).
#define SMEM_FLOATS (32 * 256)

// Map local submatrix index -> channel index for the INDS masks.
__device__ inline int chmap(int i, int n, int pa, int pb) {
    if (n == 64) return i;
    if (n == 32) return ((i >> 1) << 2) | ((i & 1) ? pb : pa);
    return (i << 2) | pa;
}

// Register-resident LU with implicit partial pivoting, lane = row.
// N lanes per matrix group; lanes {g*N..g*N+N-1} factor one NxN submatrix
// (pa/pb may differ per group -> several dets in one pass). Fully unrolled:
// all a[] indices compile-time (rule: runtime-indexed reg arrays -> scratch).
// Pivot = max |a[k]| among unused rows (consistent min-index tie-break);
// chosen row is frozen (mult=0) afterward; log|det| = sum log|pivot|.
// ~2080 independent bpermute+FMA pairs for N=64: issue-limited (~13 us),
// vs ~112 us for the old LDS round-trip serial chain.
template <int N>
__device__ float reg_lu_logabsdet(const float* __restrict__ W, int pa, int pb,
                                  int lane) {
    const int r = lane & (N - 1);        // local row
    const int gb = lane & ~(N - 1);      // group base lane
    const int row = chmap(r, N, pa, pb);
    float a[N];
#pragma unroll
    for (int j = 0; j < N; ++j) a[j] = W[row * 64 + chmap(j, N, pa, pb)];

    float logdet = 0.f;
    float used = 0.f;
#pragma unroll
    for (int k = 0; k < N; ++k) {
        // argmax |a[k]| over unused rows in this group (butterfly, all agree)
        float cand = (used != 0.f) ? -1.f : fabsf(a[k]);
        int idx = r;
#pragma unroll
        for (int off = N >> 1; off; off >>= 1) {
            float oc = __shfl_xor(cand, off, N);
            int oi = __shfl_xor(idx, off, N);
            if (oc > cand || (oc == cand && oi < idx)) { cand = oc; idx = oi; }
        }
        const int src = gb + idx;  // uniform within group
        float apk = __shfl(a[k], src, 64);
        logdet += logf(fabsf(apk));
        float rpiv = 1.f / apk;
        float mult = (used != 0.f || r == idx) ? 0.f : a[k] * rpiv;
#pragma unroll
        for (int j = k + 1; j < N; ++j)
            a[j] = fmaf(-mult, __shfl(a[j], src, 64), a[j]);
        if (r == idx) used = 1.f;
    }
    return logdet;  // uniform within each N-lane group
}

__global__ __launch_bounds__(256, 4) void InvConv1x1GridAlign_kernel(
    const float* __restrict__ x, const float* __restrict__ ld_in,
    const float* __restrict__ W, float* __restrict__ out) {
    __shared__ __align__(16) float smem[SMEM_FLOATS];
    const int tid = threadIdx.x;

    if (blockIdx.x == 0) {
        // ---- determinant block: 9 slogdets, register-LU, one wave/group ----
        float* partial = smem;
        int wid = tid >> 6;
        int lane = tid & 63;
        float part = 0.f;
        if (wid == 0) {
            part = 25281.f * reg_lu_logabsdet<64>(W, 0, 0, lane);  // (159*159)
        } else if (wid == 1) {
            // t: c%4 in {2,3} (lanes 0-31), b: {0,1} (lanes 32-63), one pass
            int g = lane >> 5;
            float ld = reg_lu_logabsdet<32>(W, g ? 0 : 2, g ? 1 : 3, lane);
            part = (__shfl(ld, 0, 64) + __shfl(ld, 32, 64)) * 159.f;
        } else if (wid == 2) {
            // l: {1,3}, r: {0,2}
            int g = lane >> 5;
            float ld = reg_lu_logabsdet<32>(W, g ? 0 : 1, g ? 2 : 3, lane);
            part = (__shfl(ld, 0, 64) + __shfl(ld, 32, 64)) * 159.f;
        } else {
            // tl:{3} tr:{2} bl:{1} br:{0} in the four 16-lane groups, one pass
            int pa = 3 - (lane >> 4);
            float ld = reg_lu_logabsdet<16>(W, pa, 0, lane);
            part = __shfl(ld, 0, 64) + __shfl(ld, 16, 64) +
                   __shfl(ld, 32, 64) + __shfl(ld, 48, 64);
        }
        if (lane == 0) partial[wid] = part;
        __syncthreads();
        if (tid < NB) {
            float dl = partial[0] + partial[1] + partial[2] + partial[3];
            out[OUT_LD_OFF + tid] = ld_in[tid] + dl;
        }
        return;
    }

    // ---- conv blocks: GEMM tile, 64 outputs x 256 sites (round-4 layout) ----
    // u[o][s] = sum_k W[o][k] * v[k][s]; v[k][s] = x[b][k^3][Y-1+dy][X-1+dx]
    // (dy=(k>>1)&1, dx=k&1; quadrant m = k&3). Lane owns sites
    // {lane, lane+64, lane+128, lane+192}: every global/LDS access is
    // lane-stride-1 -> coalesced loads/stores, conflict-free LDS.
    const int tile0 = ((int)blockIdx.x - 1) * TILE;
    const int lane = tid & 63;
    const int wid = tid >> 6;
    const int wo = __builtin_amdgcn_readfirstlane(wid << 4);  // wave-uniform

    // per-thread staging site decode (site = tile0 + tid)
    const int offm[4] = {0, 1, HW, HW + 1};
    bool vm[4];
    int baseoff;
    const float* xb;
    {
        int s = tile0 + tid;
        bool sok = s < NSITES;
        unsigned us = (unsigned)(sok ? s : 0);
        unsigned b = us / SGSQ;
        unsigned rr = us - b * SGSQ;
        unsigned Y = rr / SG;
        unsigned X = rr - Y * SG;
        xb = x + (size_t)b * (NC * PLANE);
        baseoff = ((int)Y - 1) * HW + ((int)X - 1);
        bool okT = sok && (Y >= 1), okB = sok && (Y <= HW - 1);
        bool okL = (X >= 1), okR = (X <= HW - 1);
        vm[0] = okT && okL; vm[1] = okT && okR;
        vm[2] = okB && okL; vm[3] = okB && okR;
    }

    float acc[16][4];
#pragma unroll
    for (int j = 0; j < 16; ++j)
#pragma unroll
        for (int s2 = 0; s2 < 4; ++s2) acc[j][s2] = 0.f;

#pragma unroll 1
    for (int half = 0; half < 2; ++half) {
        __syncthreads();  // previous compute done before restaging
        // ---- stage vtile[krow][tid]: 1 coalesced cond. load + 1 ds_write ----
#pragma unroll 8
        for (int krow = 0; krow < 32; ++krow) {
            const int k = (half << 5) + krow;
            const int pl = k ^ 3;
            const int m = krow & 3;  // k mod 4 (32 = 0 mod 4)
            float val = vm[m] ? xb[pl * PLANE + baseoff + offm[m]] : 0.f;
            smem[(krow << 8) + tid] = val;
        }
        __syncthreads();
        // ---- compute: per kb (4 k-steps), 16 ds_read_b32 + wave-uniform W ----
#pragma unroll 1
        for (int kb = 0; kb < 8; ++kb) {
            float v[4][4];
            const float* vb = smem + (kb << 10) + lane;
#pragma unroll
            for (int kk = 0; kk < 4; ++kk)
#pragma unroll
                for (int s2 = 0; s2 < 4; ++s2)
                    v[kk][s2] = vb[(kk << 8) + (s2 << 6)];
            const int k0 = (half << 5) + (kb << 2);
#pragma unroll
            for (int jb = 0; jb < 2; ++jb) {
                float4 w4[8];  // wave-uniform -> s_load_dwordx4 from K$
#pragma unroll
                for (int j = 0; j < 8; ++j)
                    w4[j] = *(const float4*)(W + (wo + (jb << 3) + j) * 64 + k0);
#pragma unroll
                for (int j = 0; j < 8; ++j) {
                    const int jj = (jb << 3) + j;
#pragma unroll
                    for (int kk = 0; kk < 4; ++kk) {
                        const float wjk = (kk == 0) ? w4[j].x
                                        : (kk == 1) ? w4[j].y
                                        : (kk == 2) ? w4[j].z : w4[j].w;
#pragma unroll
                        for (int s2 = 0; s2 < 4; ++s2)
                            acc[jj][s2] = fmaf(wjk, v[kk][s2], acc[jj][s2]);
                    }
                }
            }
        }
    }

    // ---- epilogue: lane's 4 sites are stride-64 -> coalesced stores ----
#pragma unroll
    for (int s2 = 0; s2 < 4; ++s2) {
        int s = tile0 + lane + (s2 << 6);
        bool sok = s < NSITES;
        unsigned us = (unsigned)(sok ? s : 0);
        unsigned b = us / SGSQ;
        unsigned rr = us - b * SGSQ;
        unsigned Y = rr / SG;
        unsigned X = rr - Y * SG;
        float* ob = out + (size_t)b * (NC * PLANE);
        int boff = ((int)Y - 1) * HW + ((int)X - 1);
        bool okT = sok && (Y >= 1), okB = sok && (Y <= HW - 1);
        bool okL = (X >= 1), okR = (X <= HW - 1);
        bool wm[4] = {okT && okL, okT && okR, okB && okL, okB && okR};
#pragma unroll
        for (int j = 0; j < 16; ++j) {
            const int o = wo + j;
            const int pl = o ^ 3;
            const int m = j & 3;  // o mod 4 (wo multiple of 16)
            if (wm[m]) ob[pl * PLANE + boff + offm[m]] = acc[j][s2];
        }
    }
}

extern "C" void kernel_launch(void* const* d_in, const int* in_sizes, int n_in,
                              void* d_out, int out_size, void* d_ws, size_t ws_size,
                              hipStream_t stream) {
    const float* x = (const float*)d_in[0];
    const float* ld = (const float*)d_in[1];
    const float* W = (const float*)d_in[2];
    float* out = (float*)d_out;
    hipLaunchKernelGGL(InvConv1x1GridAlign_kernel, dim3(NCONV + 1), dim3(256), 0,
                       stream, x, ld, W, out);
}

// Round 7
// 252.523 us; speedup vs baseline: 1.7256x; 1.7256x over previous
//
#include <hip/hip_runtime.h>
#include <math.h>

#define NB 16
#define NC 64
#define HW 160
#define PLANE (HW * HW)               // 25600
#define SG 161                        // site grid (H+1)
#define SGSQ (SG * SG)                // 25921
#define NSITES (NB * SGSQ)            // 414736
#define OUT_LD_OFF (NB * NC * PLANE)  // logdet output offset
#define TILE 256                      // sites per conv block
#define NCONV ((NSITES + TILE - 1) / TILE)  // 1621

// Union shared memory:
//   conv blocks: vtile[32][256] = 8192 floats (32 KB)
//   det block:   A64[64*65]=4160 | A32a[2*32*33]=2112 | A32b[2112] |
//                A16[4*16*17]=1088 | partial[4]  -> 9476 floats (37.9 KB)
// 4 blocks/CU at 160 KB LDS either way.
#define SMEM_FLOATS 9476

// Map local submatrix index -> channel index for the INDS masks.
__device__ inline int chmap(int i, int n, int pa, int pb) {
    if (n == 64) return i;
    if (n == 32) return ((i >> 1) << 2) | ((i & 1) ? pb : pa);
    return (i << 2) | pa;
}

// LDS LU with partial pivoting for one NxN matrix per N-lane group.
// Stride N+1 kills bank conflicts on column reads. Row updates are batched
// x4 so 8 independent ds_reads share one ~120cy latency (the rolled 1-row
// chain was the 137us wall). Rolled loops -> small code, no scratch.
// Wave-lockstep; asm waitcnts order cross-lane LDS deps.
template <int N>
__device__ float group_lu_logabsdet(const float* __restrict__ W, float* A,
                                    int pa, int pb, int lane) {
    const int r = lane & (N - 1);  // row during pivot; column during update
    constexpr int LD = N + 1;
    // load: lane = column r, rows i (global reads coalesced across lanes)
#pragma unroll 4
    for (int i = 0; i < N; ++i)
        A[i * LD + r] = W[chmap(i, N, pa, pb) * 64 + chmap(r, N, pa, pb)];
    asm volatile("s_waitcnt lgkmcnt(0) vmcnt(0)" ::: "memory");
    float logdet = 0.f;
    for (int k = 0; k < N; ++k) {
        // ---- pivot: lane = row; argmax |A[r][k]| over r >= k (butterfly) ----
        float cand = (r >= k) ? fabsf(A[r * LD + k]) : -1.f;
        int idx = r;
#pragma unroll
        for (int off = N >> 1; off; off >>= 1) {
            float oc = __shfl_xor(cand, off, N);
            int oi = __shfl_xor(idx, off, N);
            if (oc > cand || (oc == cand && oi < idx)) { cand = oc; idx = oi; }
        }
        const int p = idx;  // uniform within group
        if (p != k) {       // swap rows k,p; lane = column
            float tk = A[k * LD + r];
            float tp = A[p * LD + r];
            A[k * LD + r] = tp;
            A[p * LD + r] = tk;
        }
        asm volatile("s_waitcnt lgkmcnt(0)" ::: "memory");
        float piv = A[k * LD + k];  // group-uniform broadcast read
        logdet += logf(fabsf(piv));
        float rpiv = 1.f / piv;
        // ---- update: lane = column r > k; rows k+1..N-1 batched x4 ----
        if (r > k) {
            float wk = A[k * LD + r] * rpiv;  // A[i][r] -= A[i][k] * wk
            int i = k + 1;
            for (; i + 3 < N; i += 4) {
                float a0 = A[(i + 0) * LD + k], a1 = A[(i + 1) * LD + k],
                      a2 = A[(i + 2) * LD + k], a3 = A[(i + 3) * LD + k];
                float x0 = A[(i + 0) * LD + r], x1 = A[(i + 1) * LD + r],
                      x2 = A[(i + 2) * LD + r], x3 = A[(i + 3) * LD + r];
                A[(i + 0) * LD + r] = fmaf(-a0, wk, x0);
                A[(i + 1) * LD + r] = fmaf(-a1, wk, x1);
                A[(i + 2) * LD + r] = fmaf(-a2, wk, x2);
                A[(i + 3) * LD + r] = fmaf(-a3, wk, x3);
            }
            for (; i < N; ++i) {
                float a0 = A[i * LD + k], x0 = A[i * LD + r];
                A[i * LD + r] = fmaf(-a0, wk, x0);
            }
        }
        asm volatile("s_waitcnt lgkmcnt(0)" ::: "memory");
    }
    return logdet;  // identical across the N-lane group
}

__global__ __launch_bounds__(256, 4) void InvConv1x1GridAlign_kernel(
    const float* __restrict__ x, const float* __restrict__ ld_in,
    const float* __restrict__ W, float* __restrict__ out) {
    __shared__ __align__(16) float smem[SMEM_FLOATS];
    const int tid = threadIdx.x;

    if (blockIdx.x == 0) {
        // ---- determinant block: 9 slogdets; small ones packed per wave ----
        float* A64 = smem;
        float* A32a = smem + 4160;
        float* A32b = smem + 6272;
        float* A16 = smem + 8384;
        float* partial = smem + 9472;
        int wid = tid >> 6;
        int lane = tid & 63;
        float part = 0.f;
        if (wid == 0) {
            part = 25281.f * group_lu_logabsdet<64>(W, A64, 0, 0, lane);
        } else if (wid == 1) {
            // t: c%4 in {2,3} (lanes 0-31) || b: {0,1} (lanes 32-63)
            int g = lane >> 5;
            float ld = group_lu_logabsdet<32>(W, A32a + g * (32 * 33),
                                              g ? 0 : 2, g ? 1 : 3, lane);
            part = (__shfl(ld, 0, 64) + __shfl(ld, 32, 64)) * 159.f;
        } else if (wid == 2) {
            // l: {1,3} || r: {0,2}
            int g = lane >> 5;
            float ld = group_lu_logabsdet<32>(W, A32b + g * (32 * 33),
                                              g ? 0 : 1, g ? 2 : 3, lane);
            part = (__shfl(ld, 0, 64) + __shfl(ld, 32, 64)) * 159.f;
        } else {
            // tl:{3} tr:{2} bl:{1} br:{0} in four 16-lane groups, one pass
            int g = lane >> 4;
            float ld = group_lu_logabsdet<16>(W, A16 + g * (16 * 17),
                                              3 - g, 0, lane);
            part = __shfl(ld, 0, 64) + __shfl(ld, 16, 64) +
                   __shfl(ld, 32, 64) + __shfl(ld, 48, 64);
        }
        if (lane == 0) partial[wid] = part;
        __syncthreads();
        if (tid < NB) {
            float dl = partial[0] + partial[1] + partial[2] + partial[3];
            out[OUT_LD_OFF + tid] = ld_in[tid] + dl;
        }
        return;
    }

    // ---- conv blocks: GEMM tile, 64 outputs x 256 sites (round-4 layout) ----
    // u[o][s] = sum_k W[o][k] * v[k][s]; v[k][s] = x[b][k^3][Y-1+dy][X-1+dx]
    // (dy=(k>>1)&1, dx=k&1; quadrant m = k&3). Lane owns sites
    // {lane, lane+64, lane+128, lane+192}: every global/LDS access is
    // lane-stride-1 -> coalesced loads/stores, conflict-free LDS.
    const int tile0 = ((int)blockIdx.x - 1) * TILE;
    const int lane = tid & 63;
    const int wid = tid >> 6;
    const int wo = __builtin_amdgcn_readfirstlane(wid << 4);  // wave-uniform

    // per-thread staging site decode (site = tile0 + tid)
    const int offm[4] = {0, 1, HW, HW + 1};
    bool vm[4];
    int baseoff;
    const float* xb;
    {
        int s = tile0 + tid;
        bool sok = s < NSITES;
        unsigned us = (unsigned)(sok ? s : 0);
        unsigned b = us / SGSQ;
        unsigned rr = us - b * SGSQ;
        unsigned Y = rr / SG;
        unsigned X = rr - Y * SG;
        xb = x + (size_t)b * (NC * PLANE);
        baseoff = ((int)Y - 1) * HW + ((int)X - 1);
        bool okT = sok && (Y >= 1), okB = sok && (Y <= HW - 1);
        bool okL = (X >= 1), okR = (X <= HW - 1);
        vm[0] = okT && okL; vm[1] = okT && okR;
        vm[2] = okB && okL; vm[3] = okB && okR;
    }

    float acc[16][4];
#pragma unroll
    for (int j = 0; j < 16; ++j)
#pragma unroll
        for (int s2 = 0; s2 < 4; ++s2) acc[j][s2] = 0.f;

#pragma unroll 1
    for (int half = 0; half < 2; ++half) {
        __syncthreads();  // previous compute done before restaging
        // ---- stage vtile[krow][tid]: 1 coalesced cond. load + 1 ds_write ----
#pragma unroll 8
        for (int krow = 0; krow < 32; ++krow) {
            const int k = (half << 5) + krow;
            const int pl = k ^ 3;
            const int m = krow & 3;  // k mod 4 (32 = 0 mod 4)
            float val = vm[m] ? xb[pl * PLANE + baseoff + offm[m]] : 0.f;
            smem[(krow << 8) + tid] = val;
        }
        __syncthreads();
        // ---- compute: per kb (4 k-steps), 16 ds_read_b32 + wave-uniform W ----
#pragma unroll 1
        for (int kb = 0; kb < 8; ++kb) {
            float v[4][4];
            const float* vb = smem + (kb << 10) + lane;
#pragma unroll
            for (int kk = 0; kk < 4; ++kk)
#pragma unroll
                for (int s2 = 0; s2 < 4; ++s2)
                    v[kk][s2] = vb[(kk << 8) + (s2 << 6)];
            const int k0 = (half << 5) + (kb << 2);
#pragma unroll
            for (int jb = 0; jb < 2; ++jb) {
                float4 w4[8];  // wave-uniform -> s_load_dwordx4 from K$
#pragma unroll
                for (int j = 0; j < 8; ++j)
                    w4[j] = *(const float4*)(W + (wo + (jb << 3) + j) * 64 + k0);
#pragma unroll
                for (int j = 0; j < 8; ++j) {
                    const int jj = (jb << 3) + j;
#pragma unroll
                    for (int kk = 0; kk < 4; ++kk) {
                        const float wjk = (kk == 0) ? w4[j].x
                                        : (kk == 1) ? w4[j].y
                                        : (kk == 2) ? w4[j].z : w4[j].w;
#pragma unroll
                        for (int s2 = 0; s2 < 4; ++s2)
                            acc[jj][s2] = fmaf(wjk, v[kk][s2], acc[jj][s2]);
                    }
                }
            }
        }
    }

    // ---- epilogue: lane's 4 sites are stride-64 -> coalesced stores ----
#pragma unroll
    for (int s2 = 0; s2 < 4; ++s2) {
        int s = tile0 + lane + (s2 << 6);
        bool sok = s < NSITES;
        unsigned us = (unsigned)(sok ? s : 0);
        unsigned b = us / SGSQ;
        unsigned rr = us - b * SGSQ;
        unsigned Y = rr / SG;
        unsigned X = rr - Y * SG;
        float* ob = out + (size_t)b * (NC * PLANE);
        int boff = ((int)Y - 1) * HW + ((int)X - 1);
        bool okT = sok && (Y >= 1), okB = sok && (Y <= HW - 1);
        bool okL = (X >= 1), okR = (X <= HW - 1);
        bool wm[4] = {okT && okL, okT && okR, okB && okL, okB && okR};
#pragma unroll
        for (int j = 0; j < 16; ++j) {
            const int o = wo + j;
            const int pl = o ^ 3;
            const int m = j & 3;  // o mod 4 (wo multiple of 16)
            if (wm[m]) ob[pl * PLANE + boff + offm[m]] = acc[j][s2];
        }
    }
}

extern "C" void kernel_launch(void* const* d_in, const int* in_sizes, int n_in,
                              void* d_out, int out_size, void* d_ws, size_t ws_size,
                              hipStream_t stream) {
    const float* x = (const float*)d_in[0];
    const float* ld = (const float*)d_in[1];
    const float* W = (const float*)d_in[2];
    float* out = (float*)d_out;
    hipLaunchKernelGGL(InvConv1x1GridAlign_kernel, dim3(NCONV + 1), dim3(256), 0,
                       stream, x, ld, W, out);
}